// Round 6
// baseline (6004.222 us; speedup 1.0000x reference)
//
#include <hip/hip_runtime.h>
#include <math.h>

#define NB   8          // rows per block
#define TT   400
#define HH   128
#define CC   96
#define DD   4096
#define GJ   512
#define THRV (1.0f - 1e-5f)

__device__ __forceinline__ float sigm(float v) { return 1.0f / (1.0f + expf(-v)); }

__device__ __forceinline__ float rdlane(float v, int lane) {
    return __int_as_float(__builtin_amdgcn_readlane(__float_as_int(v), lane));
}

__global__ __launch_bounds__(512, 2)
void gru_title(const float* __restrict__ img,
               const float* __restrict__ l1w,
               const float* __restrict__ l1b,
               const float* __restrict__ wih,
               const float* __restrict__ whh,
               const float* __restrict__ bih,
               const float* __restrict__ bhh,
               const float* __restrict__ l2w,
               const float* __restrict__ l2b,
               float* __restrict__ out,
               float* __restrict__ lens)
{
    __shared__ alignas(16) float xs[NB][HH];   // h_t, flat[128m + i]
    __shared__ alignas(16) float xl[NB][HH];   // leaky(h_t)
    __shared__ alignas(16) float gs[NB][GJ];   // gate pre-activations
    __shared__ alignas(16) float chs[NB][CC];  // chars
    __shared__ int sh_stable;

    const int tid = threadIdx.x;
    const int b0  = blockIdx.x * NB;
    const float* xsf = &xs[0][0];

    // ---- combined gate weights, register/AGPR-resident (verbatim R3) ----
    float wreg[HH];
    float bj;
    if (tid < 256) {
        const float4* p0 = (const float4*)(wih + (size_t)tid * HH);
        const float4* p1 = (const float4*)(whh + (size_t)tid * HH);
        #pragma unroll
        for (int k = 0; k < HH/4; ++k) {
            float4 a = p0[k], b = p1[k];
            wreg[4*k+0] = a.x + b.x; wreg[4*k+1] = a.y + b.y;
            wreg[4*k+2] = a.z + b.z; wreg[4*k+3] = a.w + b.w;
        }
        bj = bih[tid] + bhh[tid];
    } else if (tid < 384) {
        const float4* p0 = (const float4*)(wih + (size_t)tid * HH);
        #pragma unroll
        for (int k = 0; k < HH/4; ++k) {
            float4 a = p0[k];
            wreg[4*k+0] = a.x; wreg[4*k+1] = a.y; wreg[4*k+2] = a.z; wreg[4*k+3] = a.w;
        }
        bj = bih[tid];
    } else {
        const float4* p0 = (const float4*)(whh + (size_t)(tid - 128) * HH);
        #pragma unroll
        for (int k = 0; k < HH/4; ++k) {
            float4 a = p0[k];
            wreg[4*k+0] = a.x; wreg[4*k+1] = a.y; wreg[4*k+2] = a.z; wreg[4*k+3] = a.w;
        }
        bj = bhh[tid - 128];
    }

    // chars-phase constants (threads 0..191, 4 rows each) — verbatim R3
    const int    cc_   = tid % CC;
    const int    cm0   = (tid / CC) * 4;
    const float  cbias = l2b[cc_];
    const float4* l2row = (const float4*)(l2w + (size_t)cc_ * HH);

    // ---- prologue: x0 = leaky(img @ l1w.T + l1b), 2 rows per thread ----
    {
        const int c  = tid & 127;
        const int mh = tid >> 7;            // 0..3
        const int r0 = 2*mh, r1 = r0 + 1;
        const float4* xp0 = (const float4*)(img + (size_t)(b0 + r0) * DD);
        const float4* xp1 = (const float4*)(img + (size_t)(b0 + r1) * DD);
        const float4* wp  = (const float4*)(l1w + (size_t)c * DD);
        float a0 = 0.f, b0v = 0.f, a1 = 0.f, b1v = 0.f;
        #pragma unroll 4
        for (int k = 0; k < DD/4; k += 2) {
            float4 w0 = wp[k],  w1 = wp[k+1];
            float4 u0 = xp0[k], u1 = xp0[k+1];
            float4 v0 = xp1[k], v1 = xp1[k+1];
            a0  += w0.x*u0.x + w0.y*u0.y + w0.z*u0.z + w0.w*u0.w;
            b0v += w1.x*u1.x + w1.y*u1.y + w1.z*u1.z + w1.w*u1.w;
            a1  += w0.x*v0.x + w0.y*v0.y + w0.z*v0.z + w0.w*v0.w;
            b1v += w1.x*v1.x + w1.y*v1.y + w1.z*v1.z + w1.w*v1.w;
        }
        float h0 = a0 + b0v + l1b[c];
        float h1 = a1 + b1v + l1b[c];
        xs[r0][c] = (h0 >= 0.f) ? h0 : 0.01f*h0;
        xs[r1][c] = (h1 >= 0.f) ? h1 : 0.01f*h1;
    }
    __syncthreads();

    const int wav  = tid >> 6;
    const int lane = tid & 63;
    int  len   = TT;
    bool found = false;
    int  tex   = TT;

    for (int t = 0; t < TT; ++t) {
        if (tid == 0) sh_stable = 1;

        // ---------- gates GEMM ----------
        if (t == 0) {
            // h_prev = 0: r/z/i_n from w_ih only; h_n column = b_hh_n (bias only)
            float acc[NB];
            #pragma unroll
            for (int m = 0; m < NB; ++m) acc[m] = bj;
            if (tid < 384) {
                const float4* wp = (const float4*)(wih + (size_t)tid * HH);
                #pragma unroll
                for (int k = 0; k < HH/4; ++k) {
                    float4 w = wp[k];
                    #pragma unroll
                    for (int m = 0; m < NB; ++m) {
                        float4 x = *(const float4*)&xs[m][4*k];
                        acc[m] += w.x*x.x + w.y*x.y + w.z*x.z + w.w*x.w;
                    }
                }
            }
            #pragma unroll
            for (int m = 0; m < NB; ++m) gs[m][tid] = acc[m];
        } else {
            // x is wave-uniform: each wave holds the full 1024-float x in
            // vx[16] (lane l owns flat[64r+l]); inner loop moves scalars via
            // v_readlane -> SGPR -> v_fmac's scalar operand. LDS: 16 b32/thread.
            float vx[16];
            #pragma unroll
            for (int r = 0; r < 16; ++r) vx[r] = xsf[64*r + lane];

            float acc[NB];
            #pragma unroll
            for (int m = 0; m < NB; ++m) acc[m] = bj;

            #pragma unroll
            for (int kk = 0; kk < 64; ++kk) {
                #pragma unroll
                for (int m = 0; m < NB; ++m) {
                    float x0 = rdlane(vx[2*m],     kk);   // k = kk       (flat 128m+kk)
                    float x1 = rdlane(vx[2*m + 1], kk);   // k = 64 + kk
                    acc[m] += x0 * wreg[kk] + x1 * wreg[64 + kk];
                }
            }
            #pragma unroll
            for (int m = 0; m < NB; ++m) gs[m][tid] = acc[m];
        }
        __syncthreads();   // A

        // ---------- gate nonlinearity + state update (+ fixed-point compare) ----------
        {
            const int i  = tid & 127;
            const int mh = tid >> 7;
            bool changed = false;
            #pragma unroll
            for (int g = 0; g < 2; ++g) {
                const int m = mh + 4*g;
                float r  = sigm(gs[m][i]);
                float z  = sigm(gs[m][HH + i]);
                float n  = tanhf(gs[m][2*HH + i] + r * gs[m][3*HH + i]);
                float hp = (t == 0) ? 0.f : xs[m][i];
                float h  = (1.f - z) * n + z * hp;
                changed |= (__float_as_uint(h) != __float_as_uint(hp));
                xs[m][i] = h;
                xl[m][i] = (h >= 0.f) ? h : 0.01f * h;
            }
            if (changed) sh_stable = 0;   // benign multi-writer race
        }
        __syncthreads();   // B

        // bitwise fixed point: all future chars identical to chs contents.
        if (t > 0 && sh_stable) { tex = t; break; }

        // ---------- chars = leaky(h) @ l2w.T + l2b (threads 0..191, 4 rows) ----
        if (tid < 192) {
            float a[4];
            #pragma unroll
            for (int mi = 0; mi < 4; ++mi) a[mi] = cbias;
            #pragma unroll
            for (int k = 0; k < HH/4; ++k) {
                float4 w = l2row[k];
                #pragma unroll
                for (int mi = 0; mi < 4; ++mi) {
                    float4 x = *(const float4*)&xl[cm0 + mi][4*k];
                    a[mi] += w.x*x.x + w.y*x.y + w.z*x.z + w.w*x.w;
                }
            }
            #pragma unroll
            for (int mi = 0; mi < 4; ++mi) chs[cm0 + mi][cc_] = a[mi];
        }
        __syncthreads();   // C

        // ---------- max / divide / threshold / sparse scatter / lens ----------
        {
            float v0 = chs[wav][lane];
            float v1 = (lane < 32) ? chs[wav][64 + lane] : -INFINITY;
            float mx = fmaxf(v0, v1);
            #pragma unroll
            for (int s = 32; s > 0; s >>= 1) mx = fmaxf(mx, __shfl_xor(mx, s, 64));
            float q0 = v0 / mx;
            size_t base = ((size_t)(b0 + wav) * TT + t) * CC;
            if (q0 > THRV) out[base + lane] = q0;
            if (lane < 32) {
                float q1 = v1 / mx;
                if (q1 > THRV) out[base + 64 + lane] = q1;
            }
            float q52 = __shfl(q0, 52, 64);
            if (!found && q52 == 1.0f) { found = true; len = t + 1; }
        }
        // no trailing barrier: barriers A,B of next iter separate these chs reads
        // from the next chars-phase writes.
    }

    // ---- epilogue: replicate stable chars for t in [tex, TT) ----
    if (tex < TT) {
        float v0 = chs[wav][lane];
        float v1 = (lane < 32) ? chs[wav][64 + lane] : -INFINITY;
        float mx = fmaxf(v0, v1);
        #pragma unroll
        for (int s = 32; s > 0; s >>= 1) mx = fmaxf(mx, __shfl_xor(mx, s, 64));
        size_t rowbase = (size_t)(b0 + wav) * TT * CC;
        float q0 = v0 / mx;
        if (q0 > THRV)
            for (int t = tex; t < TT; ++t) out[rowbase + (size_t)t * CC + lane] = q0;
        if (lane < 32) {
            float q1 = v1 / mx;
            if (q1 > THRV)
                for (int t = tex; t < TT; ++t) out[rowbase + (size_t)t * CC + 64 + lane] = q1;
        }
        // lens: chars at every t >= tex-1 are identical, so any char-52 argmax
        // was already recorded. len is final.
    }

    if (lane == 0) lens[b0 + wav] = (float)len;
}

extern "C" void kernel_launch(void* const* d_in, const int* in_sizes, int n_in,
                              void* d_out, int out_size, void* d_ws, size_t ws_size,
                              hipStream_t stream)
{
    const float* img = (const float*)d_in[0];
    const float* l1w = (const float*)d_in[1];
    const float* l1b = (const float*)d_in[2];
    const float* wih = (const float*)d_in[3];
    const float* whh = (const float*)d_in[4];
    const float* bih = (const float*)d_in[5];
    const float* bhh = (const float*)d_in[6];
    const float* l2w = (const float*)d_in[7];
    const float* l2b = (const float*)d_in[8];

    float* out  = (float*)d_out;
    float* lens = out + (size_t)2048 * TT * CC;

    // titles is ~99% zeros: clear everything, kernel scatters only survivors.
    hipMemsetAsync(d_out, 0, (size_t)out_size * sizeof(float), stream);

    gru_title<<<dim3(2048 / NB), dim3(512), 0, stream>>>(
        img, l1w, l1b, wih, whh, bih, bhh, l2w, l2b, out, lens);
}

// Round 7
// 2434.738 us; speedup vs baseline: 2.4661x; 2.4661x over previous
//
#include <hip/hip_runtime.h>
#include <math.h>

#define NB   8
#define TT   400
#define HH   128
#define CC   96
#define DD   4096
#define GJ   512
#define THRV (1.0f - 1e-5f)
#define XROW 36      // padded row length of swizzled x arrays (32 used)

typedef _Float16 f16x8 __attribute__((ext_vector_type(8)));
typedef float    f32x4 __attribute__((ext_vector_type(4)));

__device__ __forceinline__ float sigm(float v) { return 1.0f / (1.0f + expf(-v)); }

// split 8 fp32 into fp16 hi + fp16 lo (x = hi + lo + O(2^-24 x))
__device__ __forceinline__ void split2(float4 u0, float4 u1, f16x8& hi, f16x8& lo) {
    float x[8] = {u0.x, u0.y, u0.z, u0.w, u1.x, u1.y, u1.z, u1.w};
    #pragma unroll
    for (int e = 0; e < 8; ++e) {
        _Float16 h = (_Float16)x[e];
        hi[e] = h;
        lo[e] = (_Float16)(x[e] - (float)h);
    }
}

__global__ __launch_bounds__(512, 2)
void gru_title(const float* __restrict__ img,
               const float* __restrict__ l1w,
               const float* __restrict__ l1b,
               const float* __restrict__ wih,
               const float* __restrict__ whh,
               const float* __restrict__ bih,
               const float* __restrict__ bhh,
               const float* __restrict__ l2w,
               const float* __restrict__ l2b,
               float* __restrict__ out,
               float* __restrict__ lens)
{
    // x[m][k] stored at xsw[16*q + m][8*kt + jj] where k = 32*kt + 8*q + jj.
    // A-frag read (lane lm,lq; tile kt) = 32 contiguous bytes, 2-way banks.
    __shared__ alignas(16) float xsw[64][XROW];   // h_t (swizzled)
    __shared__ alignas(16) float xlw[64][XROW];   // leaky(h_t) (swizzled)
    __shared__ alignas(16) float xs0[NB][HH];     // x0 linear (t=0 scalar path)
    __shared__ alignas(16) float gs[NB][GJ];      // gate pre-activations
    __shared__ alignas(16) float chs[NB][CC];     // chars
    __shared__ int sh_stable;

    const int tid  = threadIdx.x;
    const int b0   = blockIdx.x * NB;
    const int w    = tid >> 6;     // wave 0..7
    const int lane = tid & 63;
    const int lm   = lane & 15;    // MFMA row/col-in-tile
    const int lq   = lane >> 4;    // MFMA quad 0..3

    // ---- t=0 scalar-path bias (thread = gate column tid), as R3 ----
    float bj0;
    if (tid < 256)      bj0 = bih[tid] + bhh[tid];
    else if (tid < 384) bj0 = bih[tid];
    else                bj0 = bhh[tid - 128];

    // ---- gate weight fragments (fp16 hi/lo), register-resident ----
    // wave w owns gate columns [64w, 64w+64): 4 n-tiles x 4 k-tiles
    f16x8 bgh[4][4], bgl[4][4];
    float gb[4];
    #pragma unroll
    for (int nt = 0; nt < 4; ++nt) {
        const int j = 64 * w + 16 * nt + lm;
        const float* wr0;
        const float* wr1 = nullptr;
        if (j < 256)      { wr0 = wih + (size_t)j * HH; wr1 = whh + (size_t)j * HH;
                            gb[nt] = bih[j] + bhh[j]; }
        else if (j < 384) { wr0 = wih + (size_t)j * HH;            gb[nt] = bih[j]; }
        else              { wr0 = whh + (size_t)(j - 128) * HH;    gb[nt] = bhh[j - 128]; }
        #pragma unroll
        for (int kt = 0; kt < 4; ++kt) {
            const int k0 = 32 * kt + 8 * lq;
            float4 u0 = *(const float4*)(wr0 + k0);
            float4 u1 = *(const float4*)(wr0 + k0 + 4);
            if (wr1) {   // wave-uniform branch (j<256 <=> w<4)
                float4 e0 = *(const float4*)(wr1 + k0);
                float4 e1 = *(const float4*)(wr1 + k0 + 4);
                u0.x += e0.x; u0.y += e0.y; u0.z += e0.z; u0.w += e0.w;
                u1.x += e1.x; u1.y += e1.y; u1.z += e1.z; u1.w += e1.w;
            }
            split2(u0, u1, bgh[nt][kt], bgl[nt][kt]);
        }
    }

    // ---- chars weight fragments: waves 0..5, col n = 16w + lm ----
    f16x8 bch[4], bcl[4];
    float cb = 0.f;
    if (w < 6) {
        const int n = 16 * w + lm;
        cb = l2b[n];
        #pragma unroll
        for (int kt = 0; kt < 4; ++kt) {
            const int k0 = 32 * kt + 8 * lq;
            float4 u0 = *(const float4*)(l2w + (size_t)n * HH + k0);
            float4 u1 = *(const float4*)(l2w + (size_t)n * HH + k0 + 4);
            split2(u0, u1, bch[kt], bcl[kt]);
        }
    }

    // ---- prologue: x0 = leaky(img @ l1w.T + l1b), 2 rows per thread ----
    {
        const int c  = tid & 127;
        const int mh = tid >> 7;
        const int r0 = 2 * mh, r1 = r0 + 1;
        const float4* xp0 = (const float4*)(img + (size_t)(b0 + r0) * DD);
        const float4* xp1 = (const float4*)(img + (size_t)(b0 + r1) * DD);
        const float4* wp  = (const float4*)(l1w + (size_t)c * DD);
        float a0 = 0.f, b0v = 0.f, a1 = 0.f, b1v = 0.f;
        #pragma unroll 4
        for (int k = 0; k < DD/4; k += 2) {
            float4 w0 = wp[k],  w1 = wp[k+1];
            float4 u0 = xp0[k], u1 = xp0[k+1];
            float4 v0 = xp1[k], v1 = xp1[k+1];
            a0  += w0.x*u0.x + w0.y*u0.y + w0.z*u0.z + w0.w*u0.w;
            b0v += w1.x*u1.x + w1.y*u1.y + w1.z*u1.z + w1.w*u1.w;
            a1  += w0.x*v0.x + w0.y*v0.y + w0.z*v0.z + w0.w*v0.w;
            b1v += w1.x*v1.x + w1.y*v1.y + w1.z*v1.z + w1.w*v1.w;
        }
        float h0 = a0 + b0v + l1b[c];
        float h1 = a1 + b1v + l1b[c];
        xs0[r0][c] = (h0 >= 0.f) ? h0 : 0.01f*h0;
        xs0[r1][c] = (h1 >= 0.f) ? h1 : 0.01f*h1;
    }
    __syncthreads();

    int  len   = TT;
    bool found = false;
    int  tex   = TT;

    for (int t = 0; t < TT; ++t) {
        if (tid == 0) sh_stable = 1;

        // ---------- gates GEMM ----------
        if (t == 0) {
            // scalar fp32 path (h_prev = 0): verbatim R3, reads xs0 + global wih
            float acc[NB];
            #pragma unroll
            for (int m = 0; m < NB; ++m) acc[m] = bj0;
            if (tid < 384) {
                const float4* wp = (const float4*)(wih + (size_t)tid * HH);
                #pragma unroll
                for (int k = 0; k < HH/4; ++k) {
                    float4 wv = wp[k];
                    #pragma unroll
                    for (int m = 0; m < NB; ++m) {
                        float4 x = *(const float4*)&xs0[m][4*k];
                        acc[m] += wv.x*x.x + wv.y*x.y + wv.z*x.z + wv.w*x.w;
                    }
                }
            }
            #pragma unroll
            for (int m = 0; m < NB; ++m) gs[m][tid] = acc[m];
        } else {
            // fp16-split-x3 MFMA: G = Xh.Wh + Xl.Wh + Xh.Wl (+bias)
            f32x4 acc[4];
            #pragma unroll
            for (int nt = 0; nt < 4; ++nt) {
                f32x4 c0 = {gb[nt], gb[nt], gb[nt], gb[nt]};
                acc[nt] = c0;
            }
            #pragma unroll
            for (int kt = 0; kt < 4; ++kt) {
                float4 u0 = *(const float4*)&xsw[16*lq + lm][8*kt];
                float4 u1 = *(const float4*)&xsw[16*lq + lm][8*kt + 4];
                f16x8 ah, al;
                split2(u0, u1, ah, al);
                #pragma unroll
                for (int nt = 0; nt < 4; ++nt) {
                    acc[nt] = __builtin_amdgcn_mfma_f32_16x16x32_f16(ah, bgh[nt][kt], acc[nt], 0, 0, 0);
                    acc[nt] = __builtin_amdgcn_mfma_f32_16x16x32_f16(al, bgh[nt][kt], acc[nt], 0, 0, 0);
                    acc[nt] = __builtin_amdgcn_mfma_f32_16x16x32_f16(ah, bgl[nt][kt], acc[nt], 0, 0, 0);
                }
            }
            // C layout: col = lane&15 (+16nt+64w), row = 4*lq + reg; keep rows<8
            if (lq < 2) {
                #pragma unroll
                for (int nt = 0; nt < 4; ++nt) {
                    #pragma unroll
                    for (int reg = 0; reg < 4; ++reg)
                        gs[4*lq + reg][64*w + 16*nt + lm] = acc[nt][reg];
                }
            }
        }
        __syncthreads();   // A

        // ---------- gate nonlinearity + fp32 state update + change detect ----------
        {
            const int i  = tid & 127;
            const int mh = tid >> 7;
            const int q_ = (i >> 3) & 3, kt_ = i >> 5, jj_ = i & 7;
            const int col = 8*kt_ + jj_;
            bool changed = false;
            #pragma unroll
            for (int g = 0; g < 2; ++g) {
                const int m   = mh + 4*g;
                const int row = 16*q_ + m;
                float r  = sigm(gs[m][i]);
                float z  = sigm(gs[m][HH + i]);
                float n  = tanhf(gs[m][2*HH + i] + r * gs[m][3*HH + i]);
                float hp = (t == 0) ? 0.f : xsw[row][col];
                float h  = (1.f - z) * n + z * hp;
                changed |= (__float_as_uint(h) != __float_as_uint(hp));
                xsw[row][col] = h;
                xlw[row][col] = (h >= 0.f) ? h : 0.01f * h;
            }
            if (changed) sh_stable = 0;   // benign multi-writer race
        }
        __syncthreads();   // B

        // bitwise fixed point: all future chars identical to chs contents.
        if (t > 0 && sh_stable) { tex = t; break; }

        // ---------- chars GEMM (waves 0..5, fp16-split-x3 MFMA) ----------
        if (w < 6) {
            f32x4 cacc = {cb, cb, cb, cb};
            #pragma unroll
            for (int kt = 0; kt < 4; ++kt) {
                float4 u0 = *(const float4*)&xlw[16*lq + lm][8*kt];
                float4 u1 = *(const float4*)&xlw[16*lq + lm][8*kt + 4];
                f16x8 ah, al;
                split2(u0, u1, ah, al);
                cacc = __builtin_amdgcn_mfma_f32_16x16x32_f16(ah, bch[kt], cacc, 0, 0, 0);
                cacc = __builtin_amdgcn_mfma_f32_16x16x32_f16(al, bch[kt], cacc, 0, 0, 0);
                cacc = __builtin_amdgcn_mfma_f32_16x16x32_f16(ah, bcl[kt], cacc, 0, 0, 0);
            }
            if (lq < 2) {
                #pragma unroll
                for (int reg = 0; reg < 4; ++reg)
                    chs[4*lq + reg][16*w + lm] = cacc[reg];
            }
        }
        __syncthreads();   // C

        // ---------- max / divide / threshold / sparse scatter / lens ----------
        {
            float v0 = chs[w][lane];
            float v1 = (lane < 32) ? chs[w][64 + lane] : -INFINITY;
            float mx = fmaxf(v0, v1);
            #pragma unroll
            for (int s = 32; s > 0; s >>= 1) mx = fmaxf(mx, __shfl_xor(mx, s, 64));
            float q0 = v0 / mx;
            size_t base = ((size_t)(b0 + w) * TT + t) * CC;
            if (q0 > THRV) out[base + lane] = q0;
            if (lane < 32) {
                float q1 = v1 / mx;
                if (q1 > THRV) out[base + 64 + lane] = q1;
            }
            float q52 = __shfl(q0, 52, 64);
            if (!found && q52 == 1.0f) { found = true; len = t + 1; }
        }
        // no trailing barrier: barriers A,B of next iter separate these chs reads
        // from the next chars-phase writes.
    }

    // ---- epilogue: replicate stable chars for t in [tex, TT) ----
    if (tex < TT) {
        float v0 = chs[w][lane];
        float v1 = (lane < 32) ? chs[w][64 + lane] : -INFINITY;
        float mx = fmaxf(v0, v1);
        #pragma unroll
        for (int s = 32; s > 0; s >>= 1) mx = fmaxf(mx, __shfl_xor(mx, s, 64));
        size_t rowbase = (size_t)(b0 + w) * TT * CC;
        float q0 = v0 / mx;
        if (q0 > THRV)
            for (int t = tex; t < TT; ++t) out[rowbase + (size_t)t * CC + lane] = q0;
        if (lane < 32) {
            float q1 = v1 / mx;
            if (q1 > THRV)
                for (int t = tex; t < TT; ++t) out[rowbase + (size_t)t * CC + 64 + lane] = q1;
        }
        // lens: chars at every t >= tex-1 are identical, so any char-52 argmax
        // was already recorded. len is final.
    }

    if (lane == 0) lens[b0 + w] = (float)len;
}

extern "C" void kernel_launch(void* const* d_in, const int* in_sizes, int n_in,
                              void* d_out, int out_size, void* d_ws, size_t ws_size,
                              hipStream_t stream)
{
    const float* img = (const float*)d_in[0];
    const float* l1w = (const float*)d_in[1];
    const float* l1b = (const float*)d_in[2];
    const float* wih = (const float*)d_in[3];
    const float* whh = (const float*)d_in[4];
    const float* bih = (const float*)d_in[5];
    const float* bhh = (const float*)d_in[6];
    const float* l2w = (const float*)d_in[7];
    const float* l2b = (const float*)d_in[8];

    float* out  = (float*)d_out;
    float* lens = out + (size_t)2048 * TT * CC;

    // titles is ~99% zeros: clear everything, kernel scatters only survivors.
    hipMemsetAsync(d_out, 0, (size_t)out_size * sizeof(float), stream);

    gru_title<<<dim3(2048 / NB), dim3(512), 0, stream>>>(
        img, l1w, l1b, wih, whh, bih, bhh, l2w, l2b, out, lens);
}

// Round 8
// 2266.931 us; speedup vs baseline: 2.6486x; 1.0740x over previous
//
#include <hip/hip_runtime.h>
#include <math.h>

#define NB   8
#define TT   400
#define HH   128
#define CC   96
#define DD   4096
#define GJ   512
#define THRV (1.0f - 1e-5f)
#define XROW 36      // padded row length of swizzled x buffers (32 used)

typedef _Float16 f16x8 __attribute__((ext_vector_type(8)));
typedef float    f32x4 __attribute__((ext_vector_type(4)));

__device__ __forceinline__ float sigm(float v) { return 1.0f / (1.0f + expf(-v)); }

// split 8 fp32 into fp16 hi + fp16 lo (x = hi + lo + O(2^-24 x))
__device__ __forceinline__ void split2(float4 u0, float4 u1, f16x8& hi, f16x8& lo) {
    float x[8] = {u0.x, u0.y, u0.z, u0.w, u1.x, u1.y, u1.z, u1.w};
    #pragma unroll
    for (int e = 0; e < 8; ++e) {
        _Float16 h = (_Float16)x[e];
        hi[e] = h;
        lo[e] = (_Float16)(x[e] - (float)h);
    }
}

__global__ __launch_bounds__(512, 2)
void gru_title(const float* __restrict__ img,
               const float* __restrict__ l1w,
               const float* __restrict__ l1b,
               const float* __restrict__ wih,
               const float* __restrict__ whh,
               const float* __restrict__ bih,
               const float* __restrict__ bhh,
               const float* __restrict__ l2w,
               const float* __restrict__ l2b,
               float* __restrict__ out,
               float* __restrict__ lens)
{
    // x[m][k] at xbuf[p][16*q + m][8*kt + jj], k = 32*kt + 8*q + jj (A-frag swizzle).
    __shared__ alignas(16) float xbuf[2][64][XROW];  // h_t double-buffered
    __shared__ alignas(16) float xs0[NB][HH];        // x0 linear (t=0 scalar path)
    __shared__ alignas(16) float gs[NB][GJ];         // t=0 gate pre-activations only
    __shared__ alignas(16) float chs[NB][CC];        // chars
    __shared__ int sh_st[2];                         // parity-buffered stable flags

    const int tid  = threadIdx.x;
    const int b0   = blockIdx.x * NB;
    const int w    = tid >> 6;     // wave 0..7
    const int lane = tid & 63;
    const int lm   = lane & 15;
    const int lq   = lane >> 4;

    // ---- t=0 scalar-path bias (thread = gate column tid) ----
    float bj0;
    if (tid < 256)      bj0 = bih[tid] + bhh[tid];
    else if (tid < 384) bj0 = bih[tid];
    else                bj0 = bhh[tid - 128];

    // ---- gate weight fragments, NEW ownership: col j = 128*nt + 16*w + lm ----
    // nt = gate type: 0=r(combined) 1=z(combined) 2=i_n(wih) 3=h_n(whh)
    f16x8 bgh[4][4], bgl[4][4];
    float gb[4];
    {
        const int j0 = 16 * w + lm;
        #pragma unroll
        for (int nt = 0; nt < 2; ++nt) {           // r, z: wih + whh combined
            const int j = j0 + 128 * nt;
            gb[nt] = bih[j] + bhh[j];
            const float* r0 = wih + (size_t)j * HH;
            const float* r1 = whh + (size_t)j * HH;
            #pragma unroll
            for (int kt = 0; kt < 4; ++kt) {
                const int k0 = 32 * kt + 8 * lq;
                float4 u0 = *(const float4*)(r0 + k0);
                float4 u1 = *(const float4*)(r0 + k0 + 4);
                float4 e0 = *(const float4*)(r1 + k0);
                float4 e1 = *(const float4*)(r1 + k0 + 4);
                u0.x += e0.x; u0.y += e0.y; u0.z += e0.z; u0.w += e0.w;
                u1.x += e1.x; u1.y += e1.y; u1.z += e1.z; u1.w += e1.w;
                split2(u0, u1, bgh[nt][kt], bgl[nt][kt]);
            }
        }
        {                                           // i_n: wih row j0+256
            const int j = j0 + 256;
            gb[2] = bih[j];
            const float* r0 = wih + (size_t)j * HH;
            #pragma unroll
            for (int kt = 0; kt < 4; ++kt) {
                const int k0 = 32 * kt + 8 * lq;
                float4 u0 = *(const float4*)(r0 + k0);
                float4 u1 = *(const float4*)(r0 + k0 + 4);
                split2(u0, u1, bgh[2][kt], bgl[2][kt]);
            }
        }
        {                                           // h_n: whh row (j0+384)-128
            const int j = j0 + 256;
            gb[3] = bhh[j];
            const float* r0 = whh + (size_t)j * HH;
            #pragma unroll
            for (int kt = 0; kt < 4; ++kt) {
                const int k0 = 32 * kt + 8 * lq;
                float4 u0 = *(const float4*)(r0 + k0);
                float4 u1 = *(const float4*)(r0 + k0 + 4);
                split2(u0, u1, bgh[3][kt], bgl[3][kt]);
            }
        }
    }

    // ---- chars weight fragments: waves 0..5, col n = 16w + lm ----
    f16x8 bch[4], bcl[4];
    float cb = 0.f;
    if (w < 6) {
        const int n = 16 * w + lm;
        cb = l2b[n];
        #pragma unroll
        for (int kt = 0; kt < 4; ++kt) {
            const int k0 = 32 * kt + 8 * lq;
            float4 u0 = *(const float4*)(l2w + (size_t)n * HH + k0);
            float4 u1 = *(const float4*)(l2w + (size_t)n * HH + k0 + 4);
            split2(u0, u1, bch[kt], bcl[kt]);
        }
    }

    // ---- prologue: x0 = leaky(img @ l1w.T + l1b), 2 rows per thread ----
    {
        const int c  = tid & 127;
        const int mh = tid >> 7;
        const int r0 = 2 * mh, r1 = r0 + 1;
        const float4* xp0 = (const float4*)(img + (size_t)(b0 + r0) * DD);
        const float4* xp1 = (const float4*)(img + (size_t)(b0 + r1) * DD);
        const float4* wp  = (const float4*)(l1w + (size_t)c * DD);
        float a0 = 0.f, b0v = 0.f, a1 = 0.f, b1v = 0.f;
        #pragma unroll 4
        for (int k = 0; k < DD/4; k += 2) {
            float4 w0 = wp[k],  w1 = wp[k+1];
            float4 u0 = xp0[k], u1 = xp0[k+1];
            float4 v0 = xp1[k], v1 = xp1[k+1];
            a0  += w0.x*u0.x + w0.y*u0.y + w0.z*u0.z + w0.w*u0.w;
            b0v += w1.x*u1.x + w1.y*u1.y + w1.z*u1.z + w1.w*u1.w;
            a1  += w0.x*v0.x + w0.y*v0.y + w0.z*v0.z + w0.w*v0.w;
            b1v += w1.x*v1.x + w1.y*v1.y + w1.z*v1.z + w1.w*v1.w;
        }
        float h0 = a0 + b0v + l1b[c];
        float h1 = a1 + b1v + l1b[c];
        xs0[r0][c] = (h0 >= 0.f) ? h0 : 0.01f*h0;
        xs0[r1][c] = (h1 >= 0.f) ? h1 : 0.01f*h1;
    }
    __syncthreads();

    // owned column address pieces (for xbuf writes)
    const int iC   = 16 * w + lm;              // owned gate-col / hidden index i
    const int qC   = (iC >> 3) & 3;
    const int xoff = 8 * (iC >> 5) + (iC & 7); // col offset within xbuf row

    float hreg[4];          // h[4*lq+reg][iC], lq<2 only — lives across steps
    int  len   = TT;
    bool found = false;
    int  tex   = TT;

    for (int t = 0; t < TT; ++t) {
        // ---------- gates + fused nonlinearity ----------
        if (t == 0) {
            // scalar fp32 path (h_prev = 0), verbatim R3/R7
            float acc[NB];
            #pragma unroll
            for (int m = 0; m < NB; ++m) acc[m] = bj0;
            if (tid < 384) {
                const float4* wp = (const float4*)(wih + (size_t)tid * HH);
                #pragma unroll
                for (int k = 0; k < HH/4; ++k) {
                    float4 wv = wp[k];
                    #pragma unroll
                    for (int m = 0; m < NB; ++m) {
                        float4 x = *(const float4*)&xs0[m][4*k];
                        acc[m] += wv.x*x.x + wv.y*x.y + wv.z*x.z + wv.w*x.w;
                    }
                }
            }
            #pragma unroll
            for (int m = 0; m < NB; ++m) gs[m][tid] = acc[m];
            __syncthreads();
            if (lq < 2) {
                #pragma unroll
                for (int reg = 0; reg < 4; ++reg) {
                    const int m = 4*lq + reg;
                    float r = sigm(gs[m][iC]);
                    float z = sigm(gs[m][HH + iC]);
                    float n = tanhf(gs[m][2*HH + iC] + r * gs[m][3*HH + iC]);
                    float h = (1.f - z) * n;          // hp = 0
                    hreg[reg] = h;
                    xbuf[0][16*qC + m][xoff] = h;
                }
            }
        } else {
            const float (*xin)[XROW] = xbuf[(t + 1) & 1];
            f32x4 acc[4];
            #pragma unroll
            for (int nt = 0; nt < 4; ++nt) {
                f32x4 c0 = {gb[nt], gb[nt], gb[nt], gb[nt]};
                acc[nt] = c0;
            }
            #pragma unroll
            for (int kt = 0; kt < 4; ++kt) {
                float4 u0 = *(const float4*)&xin[16*lq + lm][8*kt];
                float4 u1 = *(const float4*)&xin[16*lq + lm][8*kt + 4];
                f16x8 ah, al;
                split2(u0, u1, ah, al);
                #pragma unroll
                for (int nt = 0; nt < 4; ++nt) {
                    acc[nt] = __builtin_amdgcn_mfma_f32_16x16x32_f16(ah, bgh[nt][kt], acc[nt], 0, 0, 0);
                    acc[nt] = __builtin_amdgcn_mfma_f32_16x16x32_f16(al, bgh[nt][kt], acc[nt], 0, 0, 0);
                    acc[nt] = __builtin_amdgcn_mfma_f32_16x16x32_f16(ah, bgl[nt][kt], acc[nt], 0, 0, 0);
                }
            }
            // lane-local nonlinearity: acc[0..3][reg] = r,z,i_n,h_n at (row 4lq+reg, col iC)
            if (lq < 2) {
                float (*xout)[XROW] = xbuf[t & 1];
                bool changed = false;
                #pragma unroll
                for (int reg = 0; reg < 4; ++reg) {
                    const int m = 4*lq + reg;
                    float r  = sigm(acc[0][reg]);
                    float z  = sigm(acc[1][reg]);
                    float n  = tanhf(acc[2][reg] + r * acc[3][reg]);
                    float hp = hreg[reg];
                    float h  = (1.f - z) * n + z * hp;
                    changed |= (__float_as_uint(h) != __float_as_uint(hp));
                    hreg[reg] = h;
                    xout[16*qC + m][xoff] = h;
                }
                if (changed) sh_st[t & 1] = 0;   // benign multi-writer race
            }
        }
        __syncthreads();   // B1

        // bitwise fixed point: all future chars identical to chs contents.
        if (t > 0 && sh_st[t & 1]) { tex = t; break; }
        if (tid == 0) sh_st[(t + 1) & 1] = 1;   // next slot; 0-writes are a step away

        // ---------- chars GEMM (waves 0..5): leaky applied on A-frag load ----------
        if (w < 6) {
            const float (*xc)[XROW] = xbuf[t & 1];
            f32x4 cacc = {cb, cb, cb, cb};
            #pragma unroll
            for (int kt = 0; kt < 4; ++kt) {
                float4 u0 = *(const float4*)&xc[16*lq + lm][8*kt];
                float4 u1 = *(const float4*)&xc[16*lq + lm][8*kt + 4];
                u0.x = (u0.x >= 0.f) ? u0.x : 0.01f*u0.x;
                u0.y = (u0.y >= 0.f) ? u0.y : 0.01f*u0.y;
                u0.z = (u0.z >= 0.f) ? u0.z : 0.01f*u0.z;
                u0.w = (u0.w >= 0.f) ? u0.w : 0.01f*u0.w;
                u1.x = (u1.x >= 0.f) ? u1.x : 0.01f*u1.x;
                u1.y = (u1.y >= 0.f) ? u1.y : 0.01f*u1.y;
                u1.z = (u1.z >= 0.f) ? u1.z : 0.01f*u1.z;
                u1.w = (u1.w >= 0.f) ? u1.w : 0.01f*u1.w;
                f16x8 ah, al;
                split2(u0, u1, ah, al);
                cacc = __builtin_amdgcn_mfma_f32_16x16x32_f16(ah, bch[kt], cacc, 0, 0, 0);
                cacc = __builtin_amdgcn_mfma_f32_16x16x32_f16(al, bch[kt], cacc, 0, 0, 0);
                cacc = __builtin_amdgcn_mfma_f32_16x16x32_f16(ah, bcl[kt], cacc, 0, 0, 0);
            }
            if (lq < 2) {
                #pragma unroll
                for (int reg = 0; reg < 4; ++reg)
                    chs[4*lq + reg][16*w + lm] = cacc[reg];
            }
        }
        __syncthreads();   // B2

        // ---------- max / divide / threshold / sparse scatter / lens ----------
        {
            float v0 = chs[w][lane];
            float v1 = (lane < 32) ? chs[w][64 + lane] : -INFINITY;
            float mx = fmaxf(v0, v1);
            #pragma unroll
            for (int s = 32; s > 0; s >>= 1) mx = fmaxf(mx, __shfl_xor(mx, s, 64));
            float q0 = v0 / mx;
            size_t base = ((size_t)(b0 + w) * TT + t) * CC;
            if (q0 > THRV) out[base + lane] = q0;
            if (lane < 32) {
                float q1 = v1 / mx;
                if (q1 > THRV) out[base + 64 + lane] = q1;
            }
            float q52 = __shfl(q0, 52, 64);
            if (!found && q52 == 1.0f) { found = true; len = t + 1; }
        }
        // phase4 reads chs; next writer of chs is chars(t+1), separated by B1(t+1).
    }

    // ---- epilogue: replicate stable chars for t in [tex, TT) ----
    if (tex < TT) {
        float v0 = chs[w][lane];
        float v1 = (lane < 32) ? chs[w][64 + lane] : -INFINITY;
        float mx = fmaxf(v0, v1);
        #pragma unroll
        for (int s = 32; s > 0; s >>= 1) mx = fmaxf(mx, __shfl_xor(mx, s, 64));
        size_t rowbase = (size_t)(b0 + w) * TT * CC;
        float q0 = v0 / mx;
        if (q0 > THRV)
            for (int t = tex; t < TT; ++t) out[rowbase + (size_t)t * CC + lane] = q0;
        if (lane < 32) {
            float q1 = v1 / mx;
            if (q1 > THRV)
                for (int t = tex; t < TT; ++t) out[rowbase + (size_t)t * CC + 64 + lane] = q1;
        }
        // lens: chars at every t >= tex-1 are identical; len already final.
    }

    if (lane == 0) lens[b0 + w] = (float)len;
}

extern "C" void kernel_launch(void* const* d_in, const int* in_sizes, int n_in,
                              void* d_out, int out_size, void* d_ws, size_t ws_size,
                              hipStream_t stream)
{
    const float* img = (const float*)d_in[0];
    const float* l1w = (const float*)d_in[1];
    const float* l1b = (const float*)d_in[2];
    const float* wih = (const float*)d_in[3];
    const float* whh = (const float*)d_in[4];
    const float* bih = (const float*)d_in[5];
    const float* bhh = (const float*)d_in[6];
    const float* l2w = (const float*)d_in[7];
    const float* l2b = (const float*)d_in[8];

    float* out  = (float*)d_out;
    float* lens = out + (size_t)2048 * TT * CC;

    // titles is ~99% zeros: clear everything, kernel scatters only survivors.
    hipMemsetAsync(d_out, 0, (size_t)out_size * sizeof(float), stream);

    gru_title<<<dim3(2048 / NB), dim3(512), 0, stream>>>(
        img, l1w, l1b, wih, whh, bih, bhh, l2w, l2b, out, lens);
}